// Round 4
// baseline (163.163 us; speedup 1.0000x reference)
//
#include <hip/hip_runtime.h>

// Compact Bilinear Pooling via count-sketch algebra (no FFT):
//   out[b,d] = sum_{c1,c2 : (h1[c1]+h2[c2]) & 8191 == d} s1[c1]*s2[c2]*G[b,c1,c2]
//   G[b,c1,c2] = sum_{p<196} bottom1[b,c1,p] * bottom2[b,c2,p]
// R4: barrier-free K-loop. MFMA fragments are loaded DIRECTLY from global
// (k is the contiguous axis), converted fp32->bf16 in registers, with
// register-level depth-1 prefetch. No LDS staging, no in-loop __syncthreads,
// so no compiler-forced vmcnt(0) drains (the R3 65us stall). Signs fold at
// scatter time. Partials flushed with plain stores; reduce16 sums them.

#define D     8192
#define DMASK 8191
#define C     512
#define HW    196     // 14*14, contiguous innermost
#define NB    32
#define NCH   7       // ceil(196/32), tail masked
#define NSL   16      // partial slices per batch (4 t1 x 4 t2)

typedef __attribute__((ext_vector_type(8))) short bf16x8;
typedef __attribute__((ext_vector_type(4))) float f32x4;

// fp32 -> bf16 RNE
__device__ __forceinline__ unsigned short f2bf(float f) {
    unsigned u = __float_as_uint(f);
    return (unsigned short)((u + 0x7fffu + ((u >> 16) & 1u)) >> 16);
}

__device__ __forceinline__ bf16x8 pack8(float4 a, float4 b) {
    bf16x8 r;
    r[0] = (short)f2bf(a.x); r[1] = (short)f2bf(a.y);
    r[2] = (short)f2bf(a.z); r[3] = (short)f2bf(a.w);
    r[4] = (short)f2bf(b.x); r[5] = (short)f2bf(b.y);
    r[6] = (short)f2bf(b.z); r[7] = (short)f2bf(b.w);
    return r;
}

// ---------------------------------------------------------------------------
// Phase 1: recover (h[c], s[c]) branch-free. Row has exactly one +-1, so
//   s = sum(row)  (exact, +-1);  h = s * sum(row[d]*d)  (exact: int < 2^24).
// Blocks 0..511 -> S1 rows, 512..1023 -> S2 rows.
// ---------------------------------------------------------------------------
__global__ __launch_bounds__(256) void extract2(
    const float* __restrict__ S1, const float* __restrict__ S2,
    int* __restrict__ h1, float* __restrict__ s1,
    int* __restrict__ h2, float* __restrict__ s2)
{
    const int  row   = blockIdx.x & 511;
    const bool first = blockIdx.x < 512;
    const float* S = first ? S1 : S2;
    const float4* rp = (const float4*)(S + (size_t)row * D);
    const int tid = threadIdx.x;

    float4 v[8];
    #pragma unroll
    for (int ii = 0; ii < 8; ++ii) v[ii] = rp[tid + 256 * ii];

    float ssum = 0.f, wsum = 0.f;
    #pragma unroll
    for (int ii = 0; ii < 8; ++ii) {
        const float base = (float)(4 * (tid + 256 * ii));
        ssum += (v[ii].x + v[ii].y) + (v[ii].z + v[ii].w);
        wsum += v[ii].x * base + v[ii].y * (base + 1.f)
              + v[ii].z * (base + 2.f) + v[ii].w * (base + 3.f);
    }
    #pragma unroll
    for (int off = 32; off; off >>= 1) {
        ssum += __shfl_down(ssum, off, 64);
        wsum += __shfl_down(wsum, off, 64);
    }
    __shared__ float rs[4], rw[4];
    if ((tid & 63) == 0) { rs[tid >> 6] = ssum; rw[tid >> 6] = wsum; }
    __syncthreads();
    if (tid == 0) {
        const float st = (rs[0] + rs[1]) + (rs[2] + rs[3]);
        const float wt = (rw[0] + rw[1]) + (rw[2] + rw[3]);
        if (first) { h1[row] = (int)(wt * st); s1[row] = st; }
        else       { h2[row] = (int)(wt * st); s2[row] = st; }
    }
}

// ---------------------------------------------------------------------------
// Phase 2: direct-from-global bf16 MFMA GEMM + LDS-histogram scatter +
// plain-store flush to partials P[b*16 + t1*4 + t2][8192].
// Grid (4 t2, 4 t1, 32 b) = 512 blocks, 256 threads (4 waves, 64x64 each).
// ---------------------------------------------------------------------------
__global__ __launch_bounds__(256, 2) void cbp_mfma(
    const float* __restrict__ b1, const float* __restrict__ b2,
    const int* __restrict__ h1, const float* __restrict__ s1,
    const int* __restrict__ h2, const float* __restrict__ s2,
    float* __restrict__ P)
{
    const int b  = blockIdx.z;
    const int t1 = blockIdx.y;
    const int t2 = blockIdx.x;

    __shared__ float hist[D];                 // 32 KB
    __shared__ int   h1t[128], h2t[128];
    __shared__ float s1t[128], s2t[128];

    const int tid = threadIdx.x;

    // zero histogram (2048 float4); visibility enforced by the pre-scatter barrier
    #pragma unroll
    for (int i = 0; i < 8; ++i) {
        float4 z = {0.f, 0.f, 0.f, 0.f};
        ((float4*)hist)[tid + 256 * i] = z;
    }
    if (tid < 128) {
        h1t[tid] = h1[t1 * 128 + tid];  s1t[tid] = s1[t1 * 128 + tid];
        h2t[tid] = h2[t2 * 128 + tid];  s2t[tid] = s2[t2 * 128 + tid];
    }

    // MFMA lane geometry
    const int lane  = tid & 63;
    const int w     = tid >> 6;
    const int ln15  = lane & 15;
    const int qd    = lane >> 4;
    const int koff  = qd * 8;          // this lane's k-offset within a chunk
    const int mbase = (w >> 1) * 64;
    const int nbase = (w & 1) * 64;

    // per-lane fragment base pointers; chunk offsets become imm offsets
    const float* Ap[4];
    const float* Bp[4];
    #pragma unroll
    for (int i = 0; i < 4; ++i) {
        Ap[i] = b1 + ((size_t)b * C + t1 * 128 + mbase + i * 16 + ln15) * HW + koff;
        Bp[i] = b2 + ((size_t)b * C + t2 * 128 + nbase + i * 16 + ln15) * HW + koff;
    }

    f32x4 acc[4][4] = {};

    // chunk 0 (k 0..31, always in range)
    float4 la[8], lb[8];
    #pragma unroll
    for (int i = 0; i < 4; ++i) {
        la[2 * i]     = *(const float4*)(Ap[i]);
        la[2 * i + 1] = *(const float4*)(Ap[i] + 4);
        lb[2 * i]     = *(const float4*)(Bp[i]);
        lb[2 * i + 1] = *(const float4*)(Bp[i] + 4);
    }

    #pragma unroll
    for (int ch = 0; ch < NCH; ++ch) {
        // prefetch chunk ch+1 (registers; partial vmcnt wait, no barrier)
        float4 na[8], nb[8];
        if (ch + 1 < NCH) {
            const int base = (ch + 1) * 32;
            const bool v0 = (base + koff + 4) <= HW;   // tail mask (ch==5 prefetch)
            const bool v1 = (base + koff + 8) <= HW;
            const float4 z = {0.f, 0.f, 0.f, 0.f};
            #pragma unroll
            for (int i = 0; i < 4; ++i) {
                na[2 * i]     = v0 ? *(const float4*)(Ap[i] + base)     : z;
                na[2 * i + 1] = v1 ? *(const float4*)(Ap[i] + base + 4) : z;
                nb[2 * i]     = v0 ? *(const float4*)(Bp[i] + base)     : z;
                nb[2 * i + 1] = v1 ? *(const float4*)(Bp[i] + base + 4) : z;
            }
        }

        // cvt current chunk to bf16 fragments and MFMA
        bf16x8 av[4], bv[4];
        #pragma unroll
        for (int i = 0; i < 4; ++i) {
            av[i] = pack8(la[2 * i], la[2 * i + 1]);
            bv[i] = pack8(lb[2 * i], lb[2 * i + 1]);
        }
        #pragma unroll
        for (int i = 0; i < 4; ++i)
            #pragma unroll
            for (int j = 0; j < 4; ++j)
                acc[i][j] = __builtin_amdgcn_mfma_f32_16x16x32_bf16(
                    av[i], bv[j], acc[i][j], 0, 0, 0);

        if (ch + 1 < NCH) {
            #pragma unroll
            for (int t = 0; t < 8; ++t) { la[t] = na[t]; lb[t] = nb[t]; }
        }
    }

    __syncthreads();   // hist zero + h/s tables visible before atomics

    // scatter with sign fold (signs +-1: exact fp32 multiplies)
    // C/D layout: col = lane&15, row = (lane>>4)*4 + reg   [m89/m91]
    int   p2v[4]; float q2[4];
    #pragma unroll
    for (int j = 0; j < 4; ++j) {
        const int cc = nbase + j * 16 + ln15;
        p2v[j] = h2t[cc];  q2[j] = s2t[cc];
    }
    #pragma unroll
    for (int i = 0; i < 4; ++i) {
        #pragma unroll
        for (int qq = 0; qq < 4; ++qq) {
            const int rw2 = mbase + i * 16 + qd * 4 + qq;
            const int   p1 = h1t[rw2];
            const float sr = s1t[rw2];
            #pragma unroll
            for (int j = 0; j < 4; ++j)
                atomicAdd(&hist[(p1 + p2v[j]) & DMASK],
                          acc[i][j][qq] * sr * q2[j]);
        }
    }

    __syncthreads();

    // flush: plain coalesced float4 stores to this block's partial slice
    float* Pslice = P + (size_t)(b * NSL + t1 * 4 + t2) * D;
    #pragma unroll
    for (int i = 0; i < 8; ++i)
        ((float4*)Pslice)[tid + 256 * i] = ((const float4*)hist)[tid + 256 * i];
}

// ---------------------------------------------------------------------------
// Phase 3: out[b,d] = sum of 16 slices. 256 blocks x 256 threads.
// ---------------------------------------------------------------------------
__global__ __launch_bounds__(256) void reduce16(
    const float* __restrict__ P, float* __restrict__ out)
{
    const int idx4 = blockIdx.x * 256 + threadIdx.x;   // 0..65535
    const int b    = idx4 >> 11;
    const int d4   = idx4 & 2047;

    const float4* base = (const float4*)(P + (size_t)b * NSL * D) + d4;
    float4 v[NSL];
    #pragma unroll
    for (int s = 0; s < NSL; ++s) v[s] = base[s * (D / 4)];

    float4 acc = v[0];
    #pragma unroll
    for (int s = 1; s < NSL; ++s) {
        acc.x += v[s].x; acc.y += v[s].y; acc.z += v[s].z; acc.w += v[s].w;
    }
    ((float4*)out)[idx4] = acc;
}

// ---------------------------------------------------------------------------
extern "C" void kernel_launch(void* const* d_in, const int* in_sizes, int n_in,
                              void* d_out, int out_size, void* d_ws, size_t ws_size,
                              hipStream_t stream)
{
    const float* bottom1 = (const float*)d_in[0];
    const float* bottom2 = (const float*)d_in[1];
    const float* S1      = (const float*)d_in[2];
    const float* S2      = (const float*)d_in[3];
    float* out = (float*)d_out;

    float* P  = (float*)d_ws;                 // 512 * 8192 floats = 16 MB
    int*   h1 = (int*)(P + (size_t)NB * NSL * D);
    int*   h2 = h1 + C;
    float* s1 = (float*)(h2 + C);
    float* s2 = s1 + C;

    extract2<<<1024, 256, 0, stream>>>(S1, S2, h1, s1, h2, s2);
    cbp_mfma<<<dim3(4, 4, NB), 256, 0, stream>>>(bottom1, bottom2,
                                                 h1, s1, h2, s2, P);
    reduce16<<<256, 256, 0, stream>>>(P, out);
}